// Round 7
// baseline (77.076 us; speedup 1.0000x reference)
//
#include <hip/hip_runtime.h>
#include <hip/hip_bf16.h>
#include <math.h>

#define N_ROWS 8192
#define M_ROWS 4096
#define DDIM   512
#define SDIM   16

#define BM 128
#define BN 128
#define BKS 32              // K per pipeline step
#define NSTEP (DDIM / BKS)  // 16 steps

typedef __attribute__((ext_vector_type(8))) __bf16 bf16x8;
typedef __attribute__((ext_vector_type(4))) float f32x4;

__device__ __forceinline__ unsigned short f2bf_rne(float f) {
  unsigned u = __float_as_uint(f);
  u += 0x7fffu + ((u >> 16) & 1u);
  return (unsigned short)(u >> 16);
}

__device__ __forceinline__ void load_lds16(const void* g, void* l) {
  __builtin_amdgcn_global_load_lds(
      (const __attribute__((address_space(1))) void*)g,
      (__attribute__((address_space(3))) void*)l, 16, 0, 0);
}

__global__ __launch_bounds__(256) void prep_kernel(
    const float* __restrict__ x, const float* __restrict__ y,
    const float* __restrict__ samp_x, const float* __restrict__ samp_y,
    const float* __restrict__ scale,
    ushort* __restrict__ xb, ushort* __restrict__ yb,
    float* __restrict__ sqx, float* __restrict__ sqy,
    float* __restrict__ ssx, float* __restrict__ ssy)
{
  int row = blockIdx.x;
  const float* src; const float* samp; ushort* dst; float* sqo; float* sso;
  if (row < N_ROWS) {
    src = x + (size_t)row * DDIM; samp = samp_x + (size_t)row * SDIM;
    dst = xb + (size_t)row * DDIM; sqo = sqx + row; sso = ssx + row;
  } else {
    int r = row - N_ROWS;
    src = y + (size_t)r * DDIM; samp = samp_y + (size_t)r * SDIM;
    dst = yb + (size_t)r * DDIM; sqo = sqy + r; sso = ssy + r;
  }
  int tid = threadIdx.x;  // 256 threads, 2 f32 each
  float2 v = ((const float2*)src)[tid];
  ushort2 b;
  b.x = f2bf_rne(v.x);
  b.y = f2bf_rne(v.y);
  ((ushort2*)dst)[tid] = b;
  float ss = v.x * v.x + v.y * v.y;
  #pragma unroll
  for (int off = 32; off > 0; off >>= 1) ss += __shfl_down(ss, off, 64);
  __shared__ float red[4];
  if ((tid & 63) == 0) red[tid >> 6] = ss;
  __syncthreads();
  if (tid == 0) {
    float tot = red[0] + red[1] + red[2] + red[3];
    *sqo = tot;
    float acc = 0.f;
    #pragma unroll
    for (int s = 0; s < SDIM; s++) acc += samp[s] * scale[s];
    float sp = (acc > 15.f) ? acc : log1pf(expf(acc));   // softplus
    sp = fminf(fmaxf(sp, 1e-10f), 10000.f);
    *sso = sqrtf(sp);
  }
}

// 128x128 GEMM + fused Cauchy epilogue.
// Half-tile double buffer in 32 KiB LDS (same footprint as the R6 winner):
// BKS=32, 16 steps; per step: issue 4 global_load_lds for step s+1 FIRST,
// then 8 swizzled ds_read_b128 + 16 MFMA on buf[cur], then vmcnt(0) (s+1's
// loads had the whole compute phase to land — L2-resident via the XCD
// mapping below) + ONE barrier.
// XCD mapping (R6-proven): XCD k owns bx in [8k,8k+8) for all by -> per-XCD
// L2 working set = 8 A-panels (1 MB, kernel-resident) + streaming B panels.
// Swizzle g' = g ^ ((row>>1)&3) on BOTH global source and ds_read (rule #21).
__global__ __launch_bounds__(256) void cauchy_gemm(
    const ushort* __restrict__ xb, const ushort* __restrict__ yb,
    const float* __restrict__ sqx, const float* __restrict__ sqy,
    const float* __restrict__ ssx, const float* __restrict__ ssy,
    const float* __restrict__ cutoff, const float* __restrict__ phi,
    float* __restrict__ out)
{
  __shared__ ushort As[2][BM * BKS];   // 2 x 8 KiB
  __shared__ ushort Bs[2][BN * BKS];   // 2 x 8 KiB   (32 KiB total)

  const int tid  = threadIdx.x;
  const int lane = tid & 63;
  const int w    = tid >> 6;
  const int wr = w >> 1, wc = w & 1;
  const int l15 = lane & 15, l16 = lane >> 4;

  // chunked XCD swizzle (R6): xcd = bid&7, local = bid>>3.
  const int bid   = blockIdx.x;
  const int xcd   = bid & 7;
  const int local = bid >> 3;
  const int wk    = local & 31;
  const int bx = xcd * 8 + (wk & 7);           // 64 row-blocks; bx in [8k,8k+8)
  const int by = (local >> 5) * 4 + (wk >> 3); // 32 col-blocks

  // staging: 512 granules (16B) per matrix per step, 2 per thread
  const int i0 = tid, i1 = tid + 256;
  const int r0 = i0 >> 2, r1 = i1 >> 2;
  const int c0 = (i0 & 3) ^ ((r0 >> 1) & 3);   // pre-swizzled source granule
  const int c1 = (i1 & 3) ^ ((r1 >> 1) & 3);
  const ushort* aS0 = xb + (size_t)(bx * BM + r0) * DDIM + c0 * 8;
  const ushort* aS1 = xb + (size_t)(bx * BM + r1) * DDIM + c1 * 8;
  const ushort* bS0 = yb + (size_t)(by * BN + r0) * DDIM + c0 * 8;
  const ushort* bS1 = yb + (size_t)(by * BN + r1) * DDIM + c1 * 8;
  const int d0 = i0 * 8, d1 = i1 * 8;          // linear LDS dest (elements)

  // fragment ds_read offsets (loop-invariant, swizzled)
  int aoff[4], boff[4];
  #pragma unroll
  for (int a = 0; a < 4; a++) {
    int row = wr * 64 + a * 16 + l15;
    aoff[a] = row * BKS + ((l16 ^ ((row >> 1) & 3)) << 3);
  }
  #pragma unroll
  for (int b = 0; b < 4; b++) {
    int col = wc * 64 + b * 16 + l15;
    boff[b] = col * BKS + ((l16 ^ ((col >> 1) & 3)) << 3);
  }

  f32x4 acc[4][4];
  #pragma unroll
  for (int a = 0; a < 4; a++)
    #pragma unroll
    for (int b = 0; b < 4; b++) acc[a][b] = (f32x4)(0.f);

  // prologue: stage step 0 into buf 0
  load_lds16(aS0, &As[0][d0]); load_lds16(aS1, &As[0][d1]);
  load_lds16(bS0, &Bs[0][d0]); load_lds16(bS1, &Bs[0][d1]);
  asm volatile("s_waitcnt vmcnt(0)" ::: "memory");
  __builtin_amdgcn_s_barrier();

  #pragma unroll 2
  for (int s = 0; s < NSTEP; ++s) {
    const int cur = s & 1, nxt = cur ^ 1;
    if (s + 1 < NSTEP) {           // stage step s+1 (lands during this step)
      const int ko = (s + 1) * BKS;
      load_lds16(aS0 + ko, &As[nxt][d0]);
      load_lds16(aS1 + ko, &As[nxt][d1]);
      load_lds16(bS0 + ko, &Bs[nxt][d0]);
      load_lds16(bS1 + ko, &Bs[nxt][d1]);
    }
    bf16x8 af[4], bf[4];
    #pragma unroll
    for (int a = 0; a < 4; a++) af[a] = *(const bf16x8*)&As[cur][aoff[a]];
    #pragma unroll
    for (int b = 0; b < 4; b++) bf[b] = *(const bf16x8*)&Bs[cur][boff[b]];

    __builtin_amdgcn_s_setprio(1);
    #pragma unroll
    for (int a = 0; a < 4; a++)
      #pragma unroll
      for (int b = 0; b < 4; b++)
        acc[a][b] = __builtin_amdgcn_mfma_f32_16x16x32_bf16(af[a], bf[b], acc[a][b], 0, 0, 0);
    __builtin_amdgcn_s_setprio(0);

    asm volatile("s_waitcnt vmcnt(0)" ::: "memory");  // s+1 landed under MFMA
    __builtin_amdgcn_s_barrier();
  }

  // ---- fused epilogue (R6-proven) ----
  const float cut_c = fminf(fmaxf(cutoff[0], 0.f), 1000.f);
  const float q  = phi[0] * 1.4426950408889634f;   // phi * log2(e)
  const float qc = q * cut_c;
  const int rowBase = bx * BM + wr * 64;
  const int colBase = by * BN + wc * 64;

  float sq_j[4], sy_j[4];
  #pragma unroll
  for (int b = 0; b < 4; b++) {
    int j = colBase + b * 16 + l15;
    sq_j[b] = sqy[j];
    sy_j[b] = ssy[j];
  }
  #pragma unroll
  for (int a = 0; a < 4; a++) {
    float sq_i[4], sx_i[4];
    #pragma unroll
    for (int r = 0; r < 4; r++) {
      int i = rowBase + a * 16 + l16 * 4 + r;
      sq_i[r] = sqx[i];
      sx_i[r] = ssx[i];
    }
    #pragma unroll
    for (int b = 0; b < 4; b++) {
      #pragma unroll
      for (int r = 0; r < 4; r++) {
        int i = rowBase + a * 16 + l16 * 4 + r;
        int j = colBase + b * 16 + l15;
        float dot = acc[a][b][r];
        float d = __builtin_fmaf(-2.f, dot, sq_i[r] + sq_j[b]);
        float s = sx_i[r] * sy_j[b];
        float res = s * __builtin_amdgcn_rcpf(s + d);     // 1/(1+d/s)
        float earg = __builtin_fmaf(-q, res, qc);         // -phi*(res-cut)*log2e
        float u = __builtin_amdgcn_exp2f(earg);
        float o = res * __builtin_amdgcn_rcpf(1.f + u);   // res * sigmoid
        out[(size_t)i * M_ROWS + j] = o;
      }
    }
  }
}

extern "C" void kernel_launch(void* const* d_in, const int* in_sizes, int n_in,
                              void* d_out, int out_size, void* d_ws, size_t ws_size,
                              hipStream_t stream) {
  const float* x       = (const float*)d_in[0];
  const float* y       = (const float*)d_in[1];
  const float* samp_x  = (const float*)d_in[2];
  const float* samp_y  = (const float*)d_in[3];
  const float* scale   = (const float*)d_in[4];
  const float* cutoff  = (const float*)d_in[5];
  const float* phi     = (const float*)d_in[6];
  float* out = (float*)d_out;

  char* p = (char*)d_ws;
  ushort* xb = (ushort*)p; p += (size_t)N_ROWS * DDIM * 2;
  ushort* yb = (ushort*)p; p += (size_t)M_ROWS * DDIM * 2;
  float* sqx = (float*)p;  p += (size_t)N_ROWS * 4;
  float* sqy = (float*)p;  p += (size_t)M_ROWS * 4;
  float* ssx = (float*)p;  p += (size_t)N_ROWS * 4;
  float* ssy = (float*)p;  p += (size_t)M_ROWS * 4;

  prep_kernel<<<N_ROWS + M_ROWS, 256, 0, stream>>>(
      x, y, samp_x, samp_y, scale, xb, yb, sqx, sqy, ssx, ssy);

  cauchy_gemm<<<(N_ROWS / BM) * (M_ROWS / BN), 256, 0, stream>>>(
      xb, yb, sqx, sqy, ssx, ssy, cutoff, phi, out);
}

// Round 8
// 58.133 us; speedup vs baseline: 1.3259x; 1.3259x over previous
//
#include <hip/hip_runtime.h>
#include <hip/hip_bf16.h>
#include <math.h>

#define N_ROWS 8192
#define M_ROWS 4096
#define DDIM   512
#define SDIM   16

#define BM 128
#define BN 128
#define BK 64

typedef __attribute__((ext_vector_type(8))) __bf16 bf16x8;
typedef __attribute__((ext_vector_type(4))) float f32x4;

__device__ __forceinline__ unsigned short f2bf_rne(float f) {
  unsigned u = __float_as_uint(f);
  u += 0x7fffu + ((u >> 16) & 1u);
  return (unsigned short)(u >> 16);
}

__device__ __forceinline__ void load_lds16(const void* g, void* l) {
  __builtin_amdgcn_global_load_lds(
      (const __attribute__((address_space(1))) void*)g,
      (__attribute__((address_space(3))) void*)l, 16, 0, 0);
}

// One row per WAVE (4 rows per 256-thread block): 32 B/lane f32 loads,
// in-register bf16 pack (one uint4 store/lane), 6-step shfl_xor sum-square
// reduce, sample-dot by lanes 0-15 with a 4-step butterfly. No LDS, no
// serial tail, no __syncthreads.
__global__ __launch_bounds__(256) void prep_kernel(
    const float* __restrict__ x, const float* __restrict__ y,
    const float* __restrict__ samp_x, const float* __restrict__ samp_y,
    const float* __restrict__ scale,
    ushort* __restrict__ xb, ushort* __restrict__ yb,
    float* __restrict__ sqx, float* __restrict__ sqy,
    float* __restrict__ ssx, float* __restrict__ ssy)
{
  const int tid  = threadIdx.x;
  const int lane = tid & 63;
  const int row  = blockIdx.x * 4 + (tid >> 6);

  const float* src; const float* samp; ushort* dst; float* sqo; float* sso;
  if (row < N_ROWS) {
    src = x + (size_t)row * DDIM; samp = samp_x + (size_t)row * SDIM;
    dst = xb + (size_t)row * DDIM; sqo = sqx + row; sso = ssx + row;
  } else {
    int r = row - N_ROWS;
    src = y + (size_t)r * DDIM; samp = samp_y + (size_t)r * SDIM;
    dst = yb + (size_t)r * DDIM; sqo = sqy + r; sso = ssy + r;
  }

  // 8 f32 per lane (two float4), convert, one 16B store
  const float4 v0 = ((const float4*)src)[lane * 2];
  const float4 v1 = ((const float4*)src)[lane * 2 + 1];
  uint4 pk;
  pk.x = (unsigned)f2bf_rne(v0.x) | ((unsigned)f2bf_rne(v0.y) << 16);
  pk.y = (unsigned)f2bf_rne(v0.z) | ((unsigned)f2bf_rne(v0.w) << 16);
  pk.z = (unsigned)f2bf_rne(v1.x) | ((unsigned)f2bf_rne(v1.y) << 16);
  pk.w = (unsigned)f2bf_rne(v1.z) | ((unsigned)f2bf_rne(v1.w) << 16);
  ((uint4*)dst)[lane] = pk;

  float ss = v0.x * v0.x + v0.y * v0.y + v0.z * v0.z + v0.w * v0.w
           + v1.x * v1.x + v1.y * v1.y + v1.z * v1.z + v1.w * v1.w;
  #pragma unroll
  for (int m = 32; m >= 1; m >>= 1) ss += __shfl_xor(ss, m, 64);

  // sample . scale by lanes 0-15, butterfly within the 16-group
  float p = (lane < SDIM) ? samp[lane] * scale[lane] : 0.f;
  #pragma unroll
  for (int m = 8; m >= 1; m >>= 1) p += __shfl_xor(p, m, 64);

  if (lane == 0) {
    *sqo = ss;
    float sp = (p > 15.f) ? p : log1pf(expf(p));   // softplus
    sp = fminf(fmaxf(sp, 1e-10f), 10000.f);
    *sso = sqrtf(sp);
  }
}

// R6-proven GEMM (byte-identical): 128x128 tile, BK=64, 4 waves (2x2 of
// 64x64 quads), SINGLE-buffered 32 KiB LDS, two __syncthreads per tile
// (vmcnt drain inside), TLP hides the drains; phase-separated DS pipe.
// XOR swizzle g^(row&7) on BOTH global source and ds_read (rule #21).
// Chunked XCD swizzle: XCD k owns bx in [8k,8k+8) for all by.
__global__ __launch_bounds__(256, 2) void cauchy_gemm(
    const ushort* __restrict__ xb, const ushort* __restrict__ yb,
    const float* __restrict__ sqx, const float* __restrict__ sqy,
    const float* __restrict__ ssx, const float* __restrict__ ssy,
    const float* __restrict__ cutoff, const float* __restrict__ phi,
    float* __restrict__ out)
{
  __shared__ ushort As[BM * BK];
  __shared__ ushort Bs[BN * BK];
  const int tid = threadIdx.x;
  const int lane = tid & 63;
  const int w = tid >> 6;
  const int wr = w >> 1, wc = w & 1;
  const int l15 = lane & 15, l16 = lane >> 4;

  const int bid   = blockIdx.x;
  const int xcd   = bid & 7;
  const int local = bid >> 3;
  const int wk    = local & 31;
  const int bx = xcd * 8 + (wk & 7);           // 64 row-blocks; bx in [8k,8k+8)
  const int by = (local >> 5) * 4 + (wk >> 3); // 32 col-blocks

  const size_t aBase = (size_t)bx * BM * DDIM;
  const size_t bBase = (size_t)by * BN * DDIM;

  f32x4 acc[4][4];
  #pragma unroll
  for (int a = 0; a < 4; a++)
    #pragma unroll
    for (int b = 0; b < 4; b++)
      acc[a][b] = (f32x4)(0.f);

  for (int k0 = 0; k0 < DDIM; k0 += BK) {
    #pragma unroll
    for (int c = 0; c < 4; c++) {
      int idx = c * 256 + tid;           // granule index in tile
      int row = idx >> 3;                // 8 granules (64 bf16) per row
      int g = idx & 7;
      int sg = g ^ (row & 7);            // pre-swizzle the SOURCE granule
      load_lds16(xb + aBase + (size_t)row * DDIM + k0 + sg * 8, As + idx * 8);
      load_lds16(yb + bBase + (size_t)row * DDIM + k0 + sg * 8, Bs + idx * 8);
    }
    __syncthreads();  // vmcnt(0) drain + barrier

    #pragma unroll
    for (int kk = 0; kk < 2; kk++) {
      bf16x8 af[4], bfr[4];
      #pragma unroll
      for (int a = 0; a < 4; a++) {
        int row = wr * 64 + a * 16 + l15;
        int gran = kk * 4 + l16;
        int off = row * BK + ((gran ^ (row & 7)) << 3);  // elements
        af[a] = *(const bf16x8*)((const char*)As + (size_t)off * 2);
      }
      #pragma unroll
      for (int b = 0; b < 4; b++) {
        int col = wc * 64 + b * 16 + l15;
        int gran = kk * 4 + l16;
        int off = col * BK + ((gran ^ (col & 7)) << 3);
        bfr[b] = *(const bf16x8*)((const char*)Bs + (size_t)off * 2);
      }
      #pragma unroll
      for (int a = 0; a < 4; a++)
        #pragma unroll
        for (int b = 0; b < 4; b++)
          acc[a][b] = __builtin_amdgcn_mfma_f32_16x16x32_bf16(af[a], bfr[b], acc[a][b], 0, 0, 0);
    }
    __syncthreads();
  }

  // ---- fused epilogue ----
  const float cut_c = fminf(fmaxf(cutoff[0], 0.f), 1000.f);
  const float q  = phi[0] * 1.4426950408889634f;   // phi * log2(e)
  const float qc = q * cut_c;
  const int rowBase = bx * BM + wr * 64;
  const int colBase = by * BN + wc * 64;

  float sq_j[4], sy_j[4];
  #pragma unroll
  for (int b = 0; b < 4; b++) {
    int j = colBase + b * 16 + l15;
    sq_j[b] = sqy[j];
    sy_j[b] = ssy[j];
  }
  #pragma unroll
  for (int a = 0; a < 4; a++) {
    float sq_i[4], sx_i[4];
    #pragma unroll
    for (int r = 0; r < 4; r++) {
      int i = rowBase + a * 16 + l16 * 4 + r;
      sq_i[r] = sqx[i];
      sx_i[r] = ssx[i];
    }
    #pragma unroll
    for (int b = 0; b < 4; b++) {
      #pragma unroll
      for (int r = 0; r < 4; r++) {
        int i = rowBase + a * 16 + l16 * 4 + r;
        int j = colBase + b * 16 + l15;
        float dot = acc[a][b][r];
        float d = __builtin_fmaf(-2.f, dot, sq_i[r] + sq_j[b]);
        float s = sx_i[r] * sy_j[b];
        float res = s * __builtin_amdgcn_rcpf(s + d);     // 1/(1+d/s)
        float earg = __builtin_fmaf(-q, res, qc);         // -phi*(res-cut)*log2e
        float u = __builtin_amdgcn_exp2f(earg);
        float o = res * __builtin_amdgcn_rcpf(1.f + u);   // res * sigmoid
        out[(size_t)i * M_ROWS + j] = o;
      }
    }
  }
}

extern "C" void kernel_launch(void* const* d_in, const int* in_sizes, int n_in,
                              void* d_out, int out_size, void* d_ws, size_t ws_size,
                              hipStream_t stream) {
  const float* x       = (const float*)d_in[0];
  const float* y       = (const float*)d_in[1];
  const float* samp_x  = (const float*)d_in[2];
  const float* samp_y  = (const float*)d_in[3];
  const float* scale   = (const float*)d_in[4];
  const float* cutoff  = (const float*)d_in[5];
  const float* phi     = (const float*)d_in[6];
  float* out = (float*)d_out;

  char* p = (char*)d_ws;
  ushort* xb = (ushort*)p; p += (size_t)N_ROWS * DDIM * 2;
  ushort* yb = (ushort*)p; p += (size_t)M_ROWS * DDIM * 2;
  float* sqx = (float*)p;  p += (size_t)N_ROWS * 4;
  float* sqy = (float*)p;  p += (size_t)M_ROWS * 4;
  float* ssx = (float*)p;  p += (size_t)N_ROWS * 4;
  float* ssy = (float*)p;  p += (size_t)M_ROWS * 4;

  prep_kernel<<<(N_ROWS + M_ROWS) / 4, 256, 0, stream>>>(
      x, y, samp_x, samp_y, scale, xb, yb, sqx, sqy, ssx, ssy);

  cauchy_gemm<<<(N_ROWS / BM) * (M_ROWS / BN), 256, 0, stream>>>(
      xb, yb, sqx, sqy, ssx, ssy, cutoff, phi, out);
}